// Round 11
// baseline (50.166 us; speedup 1.0000x reference)
//
#include <hip/hip_runtime.h>
#include <math.h>

// Chamfer distance via MFMA, B=8, N=8192, fp32 in, fp32 scalar out.
//
// d(q,t) = |q|^2 + |t|^2 - 2 q.t  ==  dot(A_row(q), B_col(t)) with K=5:
//   A_row = (-2x_q, -2y_q, -2z_q, 1, |q|^2),  B_col = (x_t, y_t, z_t, |t|^2, 1)
// in f16 (zero-padded to K=16).  One v_mfma_f32_32x32x16_f16 -> a 32x32 tile
// of complete squared distances in fp32.
//
// prep:   both clouds -> packed f16 form (x,y,z,n,1,0,0,0) + init bits buf.
// main:   1024 blocks = dir(2) x batch(8) x rowblock(32) x colsplit(2).
//         4 waves/block; wave owns 64 rows (2 strips of 32).
//         Inner loop: software pipeline 1 deep + sched_barrier(0)-pinned
//         phases: [2 MFMA][SB][asm v_min3 fold of PREVIOUS iter's strip]
//         -- folds read results >=64 cycles after issue (outside the
//         MFMA->VALU hazard window that broke R5's same-iter asm reads),
//         and min3 halves the fold VALU vs the unfused fminf chain.
// reduce: lane-min + atomicMin bits merge, then sqrt+sum+scale.

#define NPTS   8192
#define NB     8
#define NPC    (NB * NPTS)         // 65536
#define BLOCK  256
#define CHUNK  1024
#define CS     2                   // col splits
#define COLS   (NPTS / CS)         // 4096 cols per block
#define TOTALQ (2 * NPC)           // 131072
#define EPSV   1e-12f

typedef _Float16 v8h  __attribute__((ext_vector_type(8)));
typedef float    v16f __attribute__((ext_vector_type(16)));

__global__ __launch_bounds__(BLOCK) void chamfer_prep(
    const float* __restrict__ xyz1, const float* __restrict__ xyz2,
    v8h* __restrict__ form, unsigned* __restrict__ bits)
{
    const int gid = blockIdx.x * BLOCK + threadIdx.x;    // [0, TOTALQ)
    const float* __restrict__ src = (gid < NPC) ? xyz1 : xyz2;
    const int i = (gid < NPC) ? gid : gid - NPC;
    float x = src[3 * i], y = src[3 * i + 1], z = src[3 * i + 2];
    _Float16 xh = (_Float16)x, yh = (_Float16)y, zh = (_Float16)z;
    float xf = (float)xh, yf = (float)yh, zf = (float)zh;
    float n = fmaf(xf, xf, fmaf(yf, yf, zf * zf));
    v8h bv = {};
    bv[0] = xh; bv[1] = yh; bv[2] = zh;
    bv[3] = (_Float16)n; bv[4] = (_Float16)1.0f;
    form[gid] = bv;
    bits[gid] = 0x7F7F7F7FU;       // 3.39e38f: "+inf" for nonneg uint-min
}

#define MFMA(va, vb) __builtin_amdgcn_mfma_f32_32x32x16_f16((va), (vb), vzero, 0, 0, 0)

// Fold 2 aged MFMA result tiles into the running min, one v_min3_f32 per
// element.  sa/sb elements are subregister reads of the v16f tuples.
#define FOLD(rm, sa, sb)                                              \
    _Pragma("unroll")                                                 \
    for (int r = 0; r < 16; ++r) {                                    \
        float pa = (sa)[r], pb = (sb)[r];                             \
        asm("v_min3_f32 %0, %0, %1, %2"                               \
            : "+v"((rm)[r]) : "v"(pa), "v"(pb));                      \
    }

__global__ __launch_bounds__(BLOCK, 3) void chamfer_mfma_min(
    const v8h* __restrict__ form, unsigned* __restrict__ bits)
{
    const int bid = blockIdx.x;             // [0, 1024)
    const int cs  = bid & (CS - 1);
    const int rb  = (bid >> 1) & 31;
    const int b   = (bid >> 6) & 7;
    const int dir = (bid >> 9) & 1;

    const v8h* __restrict__ qf = form + (size_t)dir * NPC + (size_t)b * NPTS;
    const v8h* __restrict__ tf = form + (size_t)(1 - dir) * NPC
                                      + (size_t)b * NPTS + cs * COLS;

    const int tid  = threadIdx.x;
    const int lane = tid & 63;
    const int w    = tid >> 6;
    const int c31  = lane & 31;
    const int rowbase = rb * 256;

    // A fragments: lanes<32 carry k=0..7 (5 live slots); lanes>=32 carry
    // k=8..15 which are all zero.
    v8h a0 = {}, a1 = {};
    if (lane < 32) {
        const _Float16 m2 = (_Float16)(-2.0f);
        v8h f = qf[rowbase + w * 64 + lane];
        a0[0] = m2 * f[0]; a0[1] = m2 * f[1]; a0[2] = m2 * f[2];
        a0[3] = (_Float16)1.0f; a0[4] = f[3];
        f = qf[rowbase + w * 64 + 32 + lane];
        a1[0] = m2 * f[0]; a1[1] = m2 * f[1]; a1[2] = m2 * f[2];
        a1[3] = (_Float16)1.0f; a1[4] = f[3];
    }

    float rm0[16], rm1[16];
#pragma unroll
    for (int r = 0; r < 16; ++r) { rm0[r] = 3.4e38f; rm1[r] = 3.4e38f; }

    __shared__ v8h bsh[CHUNK];              // 16 KB
    const v16f vzero = {};

    for (int ch = 0; ch < COLS / CHUNK; ++ch) {
        __syncthreads();
        const v8h* __restrict__ g = tf + ch * CHUNK;
#pragma unroll
        for (int k = 0; k < CHUNK / BLOCK; ++k)
            bsh[k * BLOCK + tid] = g[k * BLOCK + tid];   // b128 in, b128 out
        __syncthreads();

        // Pipeline depth 1: fold iteration cc-1's tiles while cc's MFMAs
        // are in flight.  sched_barrier(0) pins [MFMA][fold] phases.
        v16f s0a, s0b, s1a, s1b;
        {
            const v8h b0 = bsh[c31];
            const v8h b1 = bsh[32 + c31];
            s0a = MFMA(a0, b0); s0b = MFMA(a0, b1);
            s1a = MFMA(a1, b0); s1b = MFMA(a1, b1);
        }
#pragma unroll
        for (int cc = 1; cc < CHUNK / 64; ++cc) {
            const v8h b0 = bsh[cc * 64 + c31];           // broadcast b128
            const v8h b1 = bsh[cc * 64 + 32 + c31];
            v16f n0a = MFMA(a0, b0);
            v16f n0b = MFMA(a0, b1);
            __builtin_amdgcn_sched_barrier(0);
            FOLD(rm0, s0a, s0b);                         // aged >= 64 cyc
            v16f n1a = MFMA(a1, b0);
            v16f n1b = MFMA(a1, b1);
            __builtin_amdgcn_sched_barrier(0);
            FOLD(rm1, s1a, s1b);
            s0a = n0a; s0b = n0b; s1a = n1a; s1b = n1b;
        }
        __builtin_amdgcn_sched_barrier(0);
        FOLD(rm0, s0a, s0b);
        FOLD(rm1, s1a, s1b);
    }

    // Butterfly row-min across the 32 lanes sharing each row, then one
    // atomicMin per row (nonneg-float uint order; exact, deterministic).
    unsigned* dst = bits + (size_t)(dir * NB + b) * NPTS + rowbase;
#pragma unroll
    for (int s = 0; s < 2; ++s) {
#pragma unroll
        for (int r = 0; r < 16; ++r) {
            float v = s ? rm1[r] : rm0[r];
            v = fminf(v, __shfl_xor(v, 1));
            v = fminf(v, __shfl_xor(v, 2));
            v = fminf(v, __shfl_xor(v, 4));
            v = fminf(v, __shfl_xor(v, 8));
            v = fminf(v, __shfl_xor(v, 16));
            if ((lane & 31) == 0) {
                int row_local = w * 64 + s * 32 + (r & 3) + 8 * (r >> 2) + 4 * (lane >> 5);
                atomicMin(dst + row_local, __float_as_uint(fmaxf(v, 0.0f)));
            }
        }
    }
}

__global__ __launch_bounds__(BLOCK) void chamfer_reduce1(
    const unsigned* __restrict__ bits,   // [TOTALQ]
    float* __restrict__ sums)            // [512]
{
    const int idx = blockIdx.x * BLOCK + threadIdx.x;
    float m = __uint_as_float(bits[idx]);
    float val = sqrtf(fmaxf(m, EPSV));

    __shared__ float red[BLOCK];
    red[threadIdx.x] = val;
    __syncthreads();
    for (int s = BLOCK / 2; s > 0; s >>= 1) {
        if (threadIdx.x < s) red[threadIdx.x] += red[threadIdx.x + s];
        __syncthreads();
    }
    if (threadIdx.x == 0) sums[blockIdx.x] = red[0];
}

#define NSUMS (TOTALQ / BLOCK)   // 512

__global__ __launch_bounds__(NSUMS) void chamfer_finalize(
    const float* __restrict__ sums, float* __restrict__ out)
{
    __shared__ float red[NSUMS];
    red[threadIdx.x] = sums[threadIdx.x];
    __syncthreads();
    for (int s = NSUMS / 2; s > 0; s >>= 1) {
        if (threadIdx.x < s) red[threadIdx.x] += red[threadIdx.x + s];
        __syncthreads();
    }
    if (threadIdx.x == 0) out[0] = red[0] * (1.0f / (float)TOTALQ);
}

extern "C" void kernel_launch(void* const* d_in, const int* in_sizes, int n_in,
                              void* d_out, int out_size, void* d_ws, size_t ws_size,
                              hipStream_t stream) {
    const float* xyz1 = (const float*)d_in[0];
    const float* xyz2 = (const float*)d_in[1];
    float* out = (float*)d_out;

    v8h*      formbuf = (v8h*)d_ws;                      // TOTALQ v8h = 2 MB
    unsigned* bitsbuf = (unsigned*)(formbuf + TOTALQ);   // TOTALQ u32 = 512 KB
    float*    sums    = (float*)(bitsbuf + TOTALQ);      // 512 floats

    chamfer_prep<<<TOTALQ / BLOCK, BLOCK, 0, stream>>>(xyz1, xyz2, formbuf, bitsbuf);
    chamfer_mfma_min<<<2 * NB * 32 * CS, BLOCK, 0, stream>>>(formbuf, bitsbuf);
    chamfer_reduce1<<<TOTALQ / BLOCK, BLOCK, 0, stream>>>(bitsbuf, sums);
    chamfer_finalize<<<1, NSUMS, 0, stream>>>(sums, out);
}

// Round 12
// 47.186 us; speedup vs baseline: 1.0631x; 1.0631x over previous
//
#include <hip/hip_runtime.h>
#include <math.h>

// Chamfer distance via MFMA, B=8, N=8192, fp32 in, fp32 scalar out.
//
// d(q,t) = |q|^2 + |t|^2 - 2 q.t  ==  dot(A_row(q), B_col(t)) with K=5:
//   A_row = (-2x_q, -2y_q, -2z_q, 1, |q|^2),  B_col = (x_t, y_t, z_t, |t|^2, 1)
// in f16 (zero-padded to K=16).  One v_mfma_f32_32x32x16_f16 -> a 32x32 tile
// of complete squared distances in fp32.
//
// prep:   both clouds -> packed f16 form (x,y,z,n,1,0,0,0) + init bits buf.
// main:   1024 blocks = dir(2) x batch(8) x rowblock(32) x colsplit(2),
//         512 threads = 8 waves; each wave owns ONE 32-row strip.
//         Halved per-wave work (2 MFMA + 16-elem fold per iter) + 4
//         waves/SIMD -> cross-wave overlap of matrix and VALU pipes does
//         the pipelining (R9/R10 lesson: intra-wave scheduling tricks are
//         re-serialized by the compiler or race the MFMA writeback).
// reduce: lane-min + atomicMin bits merge, then sqrt+sum+scale.

#define NPTS   8192
#define NB     8
#define NPC    (NB * NPTS)         // 65536
#define BLOCK  512
#define CHUNK  1024
#define CS     2                   // col splits
#define COLS   (NPTS / CS)         // 4096 cols per block
#define TOTALQ (2 * NPC)           // 131072
#define EPSV   1e-12f

typedef _Float16 v8h  __attribute__((ext_vector_type(8)));
typedef float    v16f __attribute__((ext_vector_type(16)));

__global__ __launch_bounds__(256) void chamfer_prep(
    const float* __restrict__ xyz1, const float* __restrict__ xyz2,
    v8h* __restrict__ form, unsigned* __restrict__ bits)
{
    const int gid = blockIdx.x * 256 + threadIdx.x;      // [0, TOTALQ)
    const float* __restrict__ src = (gid < NPC) ? xyz1 : xyz2;
    const int i = (gid < NPC) ? gid : gid - NPC;
    float x = src[3 * i], y = src[3 * i + 1], z = src[3 * i + 2];
    _Float16 xh = (_Float16)x, yh = (_Float16)y, zh = (_Float16)z;
    float xf = (float)xh, yf = (float)yh, zf = (float)zh;
    float n = fmaf(xf, xf, fmaf(yf, yf, zf * zf));
    v8h bv = {};
    bv[0] = xh; bv[1] = yh; bv[2] = zh;
    bv[3] = (_Float16)n; bv[4] = (_Float16)1.0f;
    form[gid] = bv;
    bits[gid] = 0x7F7F7F7FU;       // 3.39e38f: "+inf" for nonneg uint-min
}

#define MFMA(va, vb) __builtin_amdgcn_mfma_f32_32x32x16_f16((va), (vb), vzero, 0, 0, 0)

__global__ __launch_bounds__(BLOCK, 4) void chamfer_mfma_min(
    const v8h* __restrict__ form, unsigned* __restrict__ bits)
{
    const int bid = blockIdx.x;             // [0, 1024)
    const int cs  = bid & (CS - 1);
    const int rb  = (bid >> 1) & 31;
    const int b   = (bid >> 6) & 7;
    const int dir = (bid >> 9) & 1;

    const v8h* __restrict__ qf = form + (size_t)dir * NPC + (size_t)b * NPTS;
    const v8h* __restrict__ tf = form + (size_t)(1 - dir) * NPC
                                      + (size_t)b * NPTS + cs * COLS;

    const int tid  = threadIdx.x;
    const int lane = tid & 63;
    const int w    = tid >> 6;              // wave 0..7, one 32-row strip each
    const int c31  = lane & 31;
    const int rowbase = rb * 256;

    // A fragment: lanes<32 carry k=0..7 (5 live slots); lanes>=32 carry
    // k=8..15 which are all zero.
    v8h a0 = {};
    if (lane < 32) {
        const _Float16 m2 = (_Float16)(-2.0f);
        v8h f = qf[rowbase + w * 32 + lane];
        a0[0] = m2 * f[0]; a0[1] = m2 * f[1]; a0[2] = m2 * f[2];
        a0[3] = (_Float16)1.0f; a0[4] = f[3];
    }

    float rm0[16];
#pragma unroll
    for (int r = 0; r < 16; ++r) rm0[r] = 3.4e38f;

    __shared__ v8h bsh[CHUNK];              // 16 KB
    const v16f vzero = {};

    for (int ch = 0; ch < COLS / CHUNK; ++ch) {
        __syncthreads();
        const v8h* __restrict__ g = tf + ch * CHUNK;
#pragma unroll
        for (int k = 0; k < CHUNK / BLOCK; ++k)
            bsh[k * BLOCK + tid] = g[k * BLOCK + tid];   // b128 in, b128 out
        __syncthreads();

#pragma unroll
        for (int cc = 0; cc < CHUNK / 64; ++cc) {
            const v8h b0 = bsh[cc * 64 + c31];           // broadcast b128
            const v8h b1 = bsh[cc * 64 + 32 + c31];
            v16f p = MFMA(a0, b0);
            v16f q = MFMA(a0, b1);
#pragma unroll
            for (int r = 0; r < 16; ++r)
                rm0[r] = fminf(fminf(rm0[r], p[r]), q[r]);
        }
    }

    // Butterfly row-min across the 32 lanes sharing each row, then one
    // atomicMin per row (nonneg-float uint order; exact, deterministic).
    unsigned* dst = bits + (size_t)(dir * NB + b) * NPTS + rowbase;
#pragma unroll
    for (int r = 0; r < 16; ++r) {
        float v = rm0[r];
        v = fminf(v, __shfl_xor(v, 1));
        v = fminf(v, __shfl_xor(v, 2));
        v = fminf(v, __shfl_xor(v, 4));
        v = fminf(v, __shfl_xor(v, 8));
        v = fminf(v, __shfl_xor(v, 16));
        if ((lane & 31) == 0) {
            int row_local = w * 32 + (r & 3) + 8 * (r >> 2) + 4 * (lane >> 5);
            atomicMin(dst + row_local, __float_as_uint(fmaxf(v, 0.0f)));
        }
    }
}

__global__ __launch_bounds__(256) void chamfer_reduce1(
    const unsigned* __restrict__ bits,   // [TOTALQ]
    float* __restrict__ sums)            // [512]
{
    const int idx = blockIdx.x * 256 + threadIdx.x;
    float m = __uint_as_float(bits[idx]);
    float val = sqrtf(fmaxf(m, EPSV));

    __shared__ float red[256];
    red[threadIdx.x] = val;
    __syncthreads();
    for (int s = 128; s > 0; s >>= 1) {
        if (threadIdx.x < s) red[threadIdx.x] += red[threadIdx.x + s];
        __syncthreads();
    }
    if (threadIdx.x == 0) sums[blockIdx.x] = red[0];
}

#define NSUMS (TOTALQ / 256)   // 512

__global__ __launch_bounds__(NSUMS) void chamfer_finalize(
    const float* __restrict__ sums, float* __restrict__ out)
{
    __shared__ float red[NSUMS];
    red[threadIdx.x] = sums[threadIdx.x];
    __syncthreads();
    for (int s = NSUMS / 2; s > 0; s >>= 1) {
        if (threadIdx.x < s) red[threadIdx.x] += red[threadIdx.x + s];
        __syncthreads();
    }
    if (threadIdx.x == 0) out[0] = red[0] * (1.0f / (float)TOTALQ);
}

extern "C" void kernel_launch(void* const* d_in, const int* in_sizes, int n_in,
                              void* d_out, int out_size, void* d_ws, size_t ws_size,
                              hipStream_t stream) {
    const float* xyz1 = (const float*)d_in[0];
    const float* xyz2 = (const float*)d_in[1];
    float* out = (float*)d_out;

    v8h*      formbuf = (v8h*)d_ws;                      // TOTALQ v8h = 2 MB
    unsigned* bitsbuf = (unsigned*)(formbuf + TOTALQ);   // TOTALQ u32 = 512 KB
    float*    sums    = (float*)(bitsbuf + TOTALQ);      // 512 floats

    chamfer_prep<<<TOTALQ / 256, 256, 0, stream>>>(xyz1, xyz2, formbuf, bitsbuf);
    chamfer_mfma_min<<<2 * NB * 32 * CS, BLOCK, 0, stream>>>(formbuf, bitsbuf);
    chamfer_reduce1<<<TOTALQ / 256, 256, 0, stream>>>(bitsbuf, sums);
    chamfer_finalize<<<1, NSUMS, 0, stream>>>(sums, out);
}